// Round 1
// baseline (407.098 us; speedup 1.0000x reference)
//
#include <hip/hip_runtime.h>
#include <hip/hip_bf16.h>
#include <cmath>

// Problem constants (fixed by reference)
#define NPTS 4096
#define HW   16384       // 128*128
#define WIDTH 128
#define NVIEW 4
#define KTOP 5

struct AllViews {
    // per view: row-major 3x3 (axis_i dotted with p) then T (tx,ty,tz)
    float m[NVIEW][12];
};

__global__ __launch_bounds__(256)
void colors_kernel(const float* __restrict__ displace,
                   const float* __restrict__ init_colors,
                   float* __restrict__ out_colors) {
    int n = blockIdx.x * 256 + threadIdx.x;
    if (n < NPTS) {
        float x = init_colors[n] + displace[n];
        out_colors[n] = 1.0f / (1.0f + expf(-x));
    }
}

__global__ __launch_bounds__(256)
void raster_kernel(const float* __restrict__ pcd,
                   const float* __restrict__ colors,
                   float* __restrict__ out,
                   AllViews av) {
    __shared__ float4 spts[NPTS];   // 64 KB: x,y,z(normalized),color per point

    const int v = blockIdx.x >> 6;          // 64 blocks per view
    const float* M = av.m[v];

    // Stage all transformed points into LDS (each thread 16 points, coalesced)
    #pragma unroll
    for (int j = 0; j < 16; ++j) {
        int n = threadIdx.x + (j << 8);
        float p0 = pcd[3 * n + 0];
        float p1 = pcd[3 * n + 1];
        float p2 = pcd[3 * n + 2];
        float px  = fmaf(p0, M[0], fmaf(p1, M[1], fmaf(p2, M[2], M[9])));
        float py  = fmaf(p0, M[3], fmaf(p1, M[4], fmaf(p2, M[5], M[10])));
        float pvz = fmaf(p0, M[6], fmaf(p1, M[7], fmaf(p2, M[8], M[11])));
        float pz  = (pvz - 0.01f) * (1.0f / 99.99f);   // (z - znear)/(zfar - znear)
        spts[n] = make_float4(px, py, pz, colors[n]);
    }
    __syncthreads();

    const int p  = ((blockIdx.x & 63) << 8) + threadIdx.x;  // pixel index in [0,HW)
    const int xi = p & (WIDTH - 1);
    const int yi = p >> 7;
    const float xf = 1.0f - (2.0f * (float)xi + 1.0f) * (1.0f / 128.0f);
    const float yf = 1.0f - (2.0f * (float)yi + 1.0f) * (1.0f / 128.0f);

    const float R2f   = (float)(0.02 * 0.02);
    const float invR2 = 1.0f / R2f;

    float zs[KTOP], as_[KTOP], cs[KTOP];
    #pragma unroll
    for (int k = 0; k < KTOP; ++k) { zs[k] = 3.0e38f; as_[k] = 0.0f; cs[k] = 0.0f; }

    #pragma unroll 4
    for (int n = 0; n < NPTS; ++n) {
        float4 pt = spts[n];
        float dx = pt.x - xf;
        float dy = pt.y - yf;
        float d2 = fmaf(dx, dx, dy * dy);
        // hit test; also skip if farther than current worst
        if ((d2 < R2f) & (pt.z > 0.0f) & (pt.z < zs[KTOP - 1])) {
            float nz = pt.z;
            float na = 1.0f - d2 * invR2;
            float nc = pt.w;
            // insertion by conditional swap (keeps ascending z, stable ties)
            #pragma unroll
            for (int k = 0; k < KTOP; ++k) {
                bool sw = nz < zs[k];
                float oz = zs[k], oa = as_[k], oc = cs[k];
                zs[k]  = sw ? nz : oz;
                as_[k] = sw ? na : oa;
                cs[k]  = sw ? nc : oc;
                nz = sw ? oz : nz;
                na = sw ? oa : na;
                nc = sw ? oc : nc;
            }
        }
    }

    // front-to-back over-composite, black background
    float t = 1.0f, pix = 0.0f;
    #pragma unroll
    for (int k = 0; k < KTOP; ++k) {
        pix += as_[k] * t * cs[k];
        t *= (1.0f - as_[k]);
    }

    float* o = out + 3 * ((size_t)v * HW + p);
    o[0] = pix; o[1] = pix; o[2] = pix;
}

static void compute_views(AllViews* av) {
    const double dist = 1.5;
    const double elev = 15.0 * M_PI / 180.0;
    const double az_deg[NVIEW] = {0.0, 90.0, 180.0, 270.0};
    for (int v = 0; v < NVIEW; ++v) {
        double az = az_deg[v] * M_PI / 180.0;
        double C[3] = { dist * cos(elev) * sin(az),
                        dist * sin(elev),
                        dist * cos(elev) * cos(az) };
        double nC = sqrt(C[0]*C[0] + C[1]*C[1] + C[2]*C[2]);
        double z[3] = { -C[0]/nC, -C[1]/nC, -C[2]/nC };
        double up[3] = { 0.0, 1.0, 0.0 };
        double x[3] = { up[1]*z[2] - up[2]*z[1],
                        up[2]*z[0] - up[0]*z[2],
                        up[0]*z[1] - up[1]*z[0] };
        double nx = sqrt(x[0]*x[0] + x[1]*x[1] + x[2]*x[2]);
        x[0] /= nx; x[1] /= nx; x[2] /= nx;
        double y[3] = { z[1]*x[2] - z[2]*x[1],
                        z[2]*x[0] - z[0]*x[2],
                        z[0]*x[1] - z[1]*x[0] };
        // px = dot(p, x_ax) + Tx, Tx = -dot(x_ax, C); same for y,z axes
        double* axes[3] = { x, y, z };
        for (int i = 0; i < 3; ++i) {
            av->m[v][3*i + 0] = (float)axes[i][0];
            av->m[v][3*i + 1] = (float)axes[i][1];
            av->m[v][3*i + 2] = (float)axes[i][2];
            av->m[v][9 + i] = (float)(-(axes[i][0]*C[0] + axes[i][1]*C[1] + axes[i][2]*C[2]));
        }
    }
}

extern "C" void kernel_launch(void* const* d_in, const int* in_sizes, int n_in,
                              void* d_out, int out_size, void* d_ws, size_t ws_size,
                              hipStream_t stream) {
    const float* pcd         = (const float*)d_in[0];
    const float* displace    = (const float*)d_in[1];
    const float* init_colors = (const float*)d_in[2];
    float* out = (float*)d_out;

    float* out_colors = out + (size_t)NVIEW * HW * 3;  // colors_ tail of d_out

    AllViews av;
    compute_views(&av);

    colors_kernel<<<NPTS / 256, 256, 0, stream>>>(displace, init_colors, out_colors);
    raster_kernel<<<NVIEW * (HW / 256), 256, 0, stream>>>(pcd, out_colors, out, av);
}

// Round 2
// 113.027 us; speedup vs baseline: 3.6018x; 3.6018x over previous
//
#include <hip/hip_runtime.h>
#include <hip/hip_bf16.h>
#include <cmath>

// Problem constants (fixed by reference)
#define NPTS  4096
#define HW    16384       // 128*128
#define WIDTH 128
#define NVIEW 4
#define KTOP  5
#define NBIN  128

struct AllViews {
    // per view: row-major 3x3 (axis_i dotted with p) then T (tx,ty,tz)
    float m[NVIEW][12];
};

// ---- workspace layout (bytes) ----
// 0       : tmp    float4[NVIEW*NPTS]        262144
// 262144  : srt    float4[NVIEW*NPTS]        262144
// 524288  : cnt    int[NVIEW*NBIN]           2048
// 526336  : starts int[NVIEW*(NBIN+1)]       2064
// 528400  : cursor int[NVIEW*NBIN]           2048
#define WS_TMP     0
#define WS_SRT     262144
#define WS_CNT     524288
#define WS_STARTS  526336
#define WS_CURSOR  528400

__device__ __forceinline__ int bin_of(float py) {
    int b = (int)floorf((1.0f - py) * 64.0f);
    return min(max(b, 0), NBIN - 1);
}

// transform + sigmoid + histogram
__global__ __launch_bounds__(256)
void prep_kernel(const float* __restrict__ pcd,
                 const float* __restrict__ displace,
                 const float* __restrict__ init_colors,
                 float* __restrict__ out_colors,
                 float4* __restrict__ tmp,
                 int* __restrict__ cnt,
                 AllViews av) {
    int i = blockIdx.x * 256 + threadIdx.x;     // [0, NVIEW*NPTS)
    int v = i >> 12;
    int n = i & (NPTS - 1);
    const float* M = av.m[v];

    float p0 = pcd[3 * n + 0];
    float p1 = pcd[3 * n + 1];
    float p2 = pcd[3 * n + 2];
    float px  = fmaf(p0, M[0], fmaf(p1, M[1], fmaf(p2, M[2], M[9])));
    float py  = fmaf(p0, M[3], fmaf(p1, M[4], fmaf(p2, M[5], M[10])));
    float pvz = fmaf(p0, M[6], fmaf(p1, M[7], fmaf(p2, M[8], M[11])));
    float pz  = (pvz - 0.01f) * (1.0f / 99.99f);

    float s = 1.0f / (1.0f + expf(-(init_colors[n] + displace[n])));
    if (v == 0) out_colors[n] = s;

    tmp[i] = make_float4(px, py, pz, s);
    atomicAdd(&cnt[v * NBIN + bin_of(py)], 1);
}

// exclusive prefix per view (tiny)
__global__ __launch_bounds__(64)
void scan_kernel(const int* __restrict__ cnt,
                 int* __restrict__ starts,
                 int* __restrict__ cursor) {
    int v = threadIdx.x;
    if (v < NVIEW) {
        int off = 0;
        #pragma unroll 8
        for (int b = 0; b < NBIN; ++b) {
            starts[v * (NBIN + 1) + b] = off;
            cursor[v * NBIN + b] = off;
            off += cnt[v * NBIN + b];
        }
        starts[v * (NBIN + 1) + NBIN] = off;   // = NPTS
    }
}

__global__ __launch_bounds__(256)
void scatter_kernel(const float4* __restrict__ tmp,
                    float4* __restrict__ srt,
                    int* __restrict__ cursor) {
    int i = blockIdx.x * 256 + threadIdx.x;
    int v = i >> 12;
    float4 pt = tmp[i];
    int pos = atomicAdd(&cursor[v * NBIN + bin_of(pt.y)], 1);
    srt[(size_t)v * NPTS + pos] = pt;
}

__global__ __launch_bounds__(256)
void raster_kernel(const float4* __restrict__ srt,
                   const int* __restrict__ starts,
                   float* __restrict__ out) {
    const int p  = blockIdx.x * 256 + threadIdx.x;   // [0, NVIEW*HW)
    const int v  = p >> 14;
    const int q  = p & (HW - 1);
    const int yi = q >> 7;
    const int xi = q & (WIDTH - 1);

    const float xf = 1.0f - (2.0f * (float)xi + 1.0f) * (1.0f / 128.0f);
    const float yf = 1.0f - (2.0f * (float)yi + 1.0f) * (1.0f / 128.0f);

    const float R2f   = (float)(0.02 * 0.02);
    const float invR2 = 1.0f / R2f;

    const int lo = starts[v * (NBIN + 1) + max(yi - 1, 0)];
    const int hi = starts[v * (NBIN + 1) + min(yi + 1, NBIN - 1) + 1];
    const float4* __restrict__ base = srt + (size_t)v * NPTS;

    float zs[KTOP], as_[KTOP], cs[KTOP];
    #pragma unroll
    for (int k = 0; k < KTOP; ++k) { zs[k] = 3.0e38f; as_[k] = 0.0f; cs[k] = 0.0f; }

    #pragma unroll 4
    for (int j = lo; j < hi; ++j) {
        float4 pt = base[j];
        float dx = pt.x - xf;
        float dy = pt.y - yf;
        float d2 = fmaf(dx, dx, dy * dy);
        if ((d2 < R2f) & (pt.z > 0.0f) & (pt.z < zs[KTOP - 1])) {
            float nz = pt.z;
            float na = 1.0f - d2 * invR2;
            float nc = pt.w;
            #pragma unroll
            for (int k = 0; k < KTOP; ++k) {
                bool sw = nz < zs[k];
                float oz = zs[k], oa = as_[k], oc = cs[k];
                zs[k]  = sw ? nz : oz;
                as_[k] = sw ? na : oa;
                cs[k]  = sw ? nc : oc;
                nz = sw ? oz : nz;
                na = sw ? oa : na;
                nc = sw ? oc : nc;
            }
        }
    }

    float t = 1.0f, pix = 0.0f;
    #pragma unroll
    for (int k = 0; k < KTOP; ++k) {
        pix += as_[k] * t * cs[k];
        t *= (1.0f - as_[k]);
    }

    float* o = out + 3 * (size_t)p;
    o[0] = pix; o[1] = pix; o[2] = pix;
}

static void compute_views(AllViews* av) {
    const double dist = 1.5;
    const double elev = 15.0 * M_PI / 180.0;
    const double az_deg[NVIEW] = {0.0, 90.0, 180.0, 270.0};
    for (int v = 0; v < NVIEW; ++v) {
        double az = az_deg[v] * M_PI / 180.0;
        double C[3] = { dist * cos(elev) * sin(az),
                        dist * sin(elev),
                        dist * cos(elev) * cos(az) };
        double nC = sqrt(C[0]*C[0] + C[1]*C[1] + C[2]*C[2]);
        double z[3] = { -C[0]/nC, -C[1]/nC, -C[2]/nC };
        double up[3] = { 0.0, 1.0, 0.0 };
        double x[3] = { up[1]*z[2] - up[2]*z[1],
                        up[2]*z[0] - up[0]*z[2],
                        up[0]*z[1] - up[1]*z[0] };
        double nx = sqrt(x[0]*x[0] + x[1]*x[1] + x[2]*x[2]);
        x[0] /= nx; x[1] /= nx; x[2] /= nx;
        double y[3] = { z[1]*x[2] - z[2]*x[1],
                        z[2]*x[0] - z[0]*x[2],
                        z[0]*x[1] - z[1]*x[0] };
        double* axes[3] = { x, y, z };
        for (int i = 0; i < 3; ++i) {
            av->m[v][3*i + 0] = (float)axes[i][0];
            av->m[v][3*i + 1] = (float)axes[i][1];
            av->m[v][3*i + 2] = (float)axes[i][2];
            av->m[v][9 + i] = (float)(-(axes[i][0]*C[0] + axes[i][1]*C[1] + axes[i][2]*C[2]));
        }
    }
}

extern "C" void kernel_launch(void* const* d_in, const int* in_sizes, int n_in,
                              void* d_out, int out_size, void* d_ws, size_t ws_size,
                              hipStream_t stream) {
    const float* pcd         = (const float*)d_in[0];
    const float* displace    = (const float*)d_in[1];
    const float* init_colors = (const float*)d_in[2];
    float* out = (float*)d_out;
    float* out_colors = out + (size_t)NVIEW * HW * 3;

    char* ws = (char*)d_ws;
    float4* tmp   = (float4*)(ws + WS_TMP);
    float4* srt   = (float4*)(ws + WS_SRT);
    int* cnt      = (int*)(ws + WS_CNT);
    int* starts   = (int*)(ws + WS_STARTS);
    int* cursor   = (int*)(ws + WS_CURSOR);

    AllViews av;
    compute_views(&av);

    hipMemsetAsync(cnt, 0, NVIEW * NBIN * sizeof(int), stream);
    prep_kernel<<<NVIEW * NPTS / 256, 256, 0, stream>>>(pcd, displace, init_colors,
                                                        out_colors, tmp, cnt, av);
    scan_kernel<<<1, 64, 0, stream>>>(cnt, starts, cursor);
    scatter_kernel<<<NVIEW * NPTS / 256, 256, 0, stream>>>(tmp, srt, cursor);
    raster_kernel<<<NVIEW * HW / 256, 256, 0, stream>>>(srt, starts, out);
}

// Round 3
// 94.041 us; speedup vs baseline: 4.3290x; 1.2019x over previous
//
#include <hip/hip_runtime.h>
#include <hip/hip_bf16.h>
#include <cmath>

// Problem constants (fixed by reference)
#define NPTS  4096
#define HW    16384       // 128*128
#define WIDTH 128
#define NVIEW 4
#define KTOP  5
#define NBIN  128
#define BUFSZ 1024        // LDS staging capacity per raster block (span max ~300 in practice)

struct AllViews {
    // per view: row-major 3x3 (axis_i dotted with p) then T (tx,ty,tz)
    float m[NVIEW][12];
};

// ---- workspace layout (bytes) ----
// 0      : srt    float4[NVIEW*NPTS]        262144
// 262144 : starts int[NVIEW*(NBIN+1)]       2064
#define WS_SRT     0
#define WS_STARTS  262144

__device__ __forceinline__ int bin_of(float py) {
    int b = (int)floorf((1.0f - py) * 64.0f);
    return min(max(b, 0), NBIN - 1);
}

// One block per view (1024 threads): transform + sigmoid + histogram +
// block-wide exclusive scan + counting-sort scatter. No global scratch deps.
__global__ __launch_bounds__(1024)
void prep_all(const float* __restrict__ pcd,
              const float* __restrict__ displace,
              const float* __restrict__ init_colors,
              float* __restrict__ out_colors,
              float4* __restrict__ srt,
              int* __restrict__ starts,
              AllViews av) {
    __shared__ int hist[NBIN];
    __shared__ int scanv[NBIN];
    __shared__ int cursor[NBIN];

    const int v   = blockIdx.x;
    const int tid = threadIdx.x;
    const float* M = av.m[v];

    if (tid < NBIN) hist[tid] = 0;
    __syncthreads();

    float4 pts[4];
    int    bins[4];

    #pragma unroll
    for (int t = 0; t < 4; ++t) {
        int n = tid + (t << 10);                  // [0, NPTS)
        float p0 = pcd[3 * n + 0];
        float p1 = pcd[3 * n + 1];
        float p2 = pcd[3 * n + 2];
        float px  = fmaf(p0, M[0], fmaf(p1, M[1], fmaf(p2, M[2], M[9])));
        float py  = fmaf(p0, M[3], fmaf(p1, M[4], fmaf(p2, M[5], M[10])));
        float pvz = fmaf(p0, M[6], fmaf(p1, M[7], fmaf(p2, M[8], M[11])));
        float pz  = (pvz - 0.01f) * (1.0f / 99.99f);

        float s = 1.0f / (1.0f + expf(-(init_colors[n] + displace[n])));
        if (v == 0) out_colors[n] = s;

        int b = bin_of(py);
        pts[t]  = make_float4(px, py, pz, s);
        bins[t] = b;
        atomicAdd(&hist[b], 1);
    }
    __syncthreads();

    // Hillis-Steele inclusive scan over 128 bins (all threads hit barriers)
    if (tid < NBIN) scanv[tid] = hist[tid];
    __syncthreads();
    for (int off = 1; off < NBIN; off <<= 1) {
        int x = 0;
        if (tid < NBIN) {
            x = scanv[tid];
            if (tid >= off) x += scanv[tid - off];
        }
        __syncthreads();
        if (tid < NBIN) scanv[tid] = x;
        __syncthreads();
    }
    if (tid < NBIN) {
        int excl = scanv[tid] - hist[tid];
        cursor[tid] = excl;
        starts[v * (NBIN + 1) + tid] = excl;
        if (tid == 0) starts[v * (NBIN + 1) + NBIN] = NPTS;
    }
    __syncthreads();

    #pragma unroll
    for (int t = 0; t < 4; ++t) {
        int pos = atomicAdd(&cursor[bins[t]], 1);
        srt[(size_t)v * NPTS + pos] = pts[t];
    }
}

// One block per (view, row-pair). Candidate span (4 y-bins) staged in LDS.
__global__ __launch_bounds__(256)
void raster_kernel(const float4* __restrict__ srt,
                   const int* __restrict__ starts,
                   float* __restrict__ out) {
    __shared__ float4 buf[BUFSZ + 1];   // +1 sentinel slot for prefetch overrun

    const int r  = blockIdx.x & 63;     // row-pair within view
    const int v  = blockIdx.x >> 6;
    const int y0 = r << 1;
    const int tid = threadIdx.x;
    const int* __restrict__ st = starts + v * (NBIN + 1);

    const int blo = st[max(y0 - 1, 0)];
    const int bhi = st[min(y0 + 2, NBIN - 1) + 1];
    const int cnt = bhi - blo;

    const float4* __restrict__ base = srt + (size_t)v * NPTS;
    for (int j = tid; j < cnt && j < BUFSZ; j += 256)
        buf[j] = base[blo + j];
    __syncthreads();

    const int yi = y0 + (tid >> 7);
    const int xi = tid & (WIDTH - 1);
    const float xf = 1.0f - (2.0f * (float)xi + 1.0f) * (1.0f / 128.0f);
    const float yf = 1.0f - (2.0f * (float)yi + 1.0f) * (1.0f / 128.0f);

    const float R2f   = (float)(0.02 * 0.02);
    const float invR2 = 1.0f / R2f;

    // per-pixel candidate sub-span (wave-uniform), as LDS indices
    const int jb = st[max(yi - 1, 0)] - blo;
    const int jePix = st[min(yi + 1, NBIN - 1) + 1] - blo;
    const int je = min(jePix, BUFSZ);

    float zs[KTOP], as_[KTOP], cs[KTOP];
    #pragma unroll
    for (int k = 0; k < KTOP; ++k) { zs[k] = 3.0e38f; as_[k] = 0.0f; cs[k] = 0.0f; }

    if (jb < je) {
        float4 cur = buf[jb];
        for (int j = jb; j < je; ++j) {
            float4 nxt = buf[j + 1];            // sentinel-safe prefetch
            float dx = cur.x - xf;
            float dy = cur.y - yf;
            float d2 = fmaf(dx, dx, dy * dy);
            if ((d2 < R2f) & (cur.z > 0.0f) & (cur.z < zs[KTOP - 1])) {
                float nz = cur.z;
                float na = 1.0f - d2 * invR2;
                float nc = cur.w;
                #pragma unroll
                for (int k = 0; k < KTOP; ++k) {
                    bool sw = nz < zs[k];
                    float oz = zs[k], oa = as_[k], oc = cs[k];
                    zs[k]  = sw ? nz : oz;
                    as_[k] = sw ? na : oa;
                    cs[k]  = sw ? nc : oc;
                    nz = sw ? oz : nz;
                    na = sw ? oa : na;
                    nc = sw ? oc : nc;
                }
            }
            cur = nxt;
        }
    }
    // overflow tail (span larger than LDS buffer — never hit for this data)
    for (int j = BUFSZ; j < jePix; ++j) {
        float4 pt = base[blo + j];
        float dx = pt.x - xf;
        float dy = pt.y - yf;
        float d2 = fmaf(dx, dx, dy * dy);
        if ((d2 < R2f) & (pt.z > 0.0f) & (pt.z < zs[KTOP - 1])) {
            float nz = pt.z, na = 1.0f - d2 * invR2, nc = pt.w;
            #pragma unroll
            for (int k = 0; k < KTOP; ++k) {
                bool sw = nz < zs[k];
                float oz = zs[k], oa = as_[k], oc = cs[k];
                zs[k]  = sw ? nz : oz;
                as_[k] = sw ? na : oa;
                cs[k]  = sw ? nc : oc;
                nz = sw ? oz : nz;
                na = sw ? oa : na;
                nc = sw ? oc : nc;
            }
        }
    }

    float t = 1.0f, pix = 0.0f;
    #pragma unroll
    for (int k = 0; k < KTOP; ++k) {
        pix += as_[k] * t * cs[k];
        t *= (1.0f - as_[k]);
    }

    const int p = (blockIdx.x << 8) + tid;      // = v*HW + y0*128... (contiguous)
    float* o = out + 3 * (size_t)p;
    o[0] = pix; o[1] = pix; o[2] = pix;
}

static void compute_views(AllViews* av) {
    const double dist = 1.5;
    const double elev = 15.0 * M_PI / 180.0;
    const double az_deg[NVIEW] = {0.0, 90.0, 180.0, 270.0};
    for (int v = 0; v < NVIEW; ++v) {
        double az = az_deg[v] * M_PI / 180.0;
        double C[3] = { dist * cos(elev) * sin(az),
                        dist * sin(elev),
                        dist * cos(elev) * cos(az) };
        double nC = sqrt(C[0]*C[0] + C[1]*C[1] + C[2]*C[2]);
        double z[3] = { -C[0]/nC, -C[1]/nC, -C[2]/nC };
        double up[3] = { 0.0, 1.0, 0.0 };
        double x[3] = { up[1]*z[2] - up[2]*z[1],
                        up[2]*z[0] - up[0]*z[2],
                        up[0]*z[1] - up[1]*z[0] };
        double nx = sqrt(x[0]*x[0] + x[1]*x[1] + x[2]*x[2]);
        x[0] /= nx; x[1] /= nx; x[2] /= nx;
        double y[3] = { z[1]*x[2] - z[2]*x[1],
                        z[2]*x[0] - z[0]*x[2],
                        z[0]*x[1] - z[1]*x[0] };
        double* axes[3] = { x, y, z };
        for (int i = 0; i < 3; ++i) {
            av->m[v][3*i + 0] = (float)axes[i][0];
            av->m[v][3*i + 1] = (float)axes[i][1];
            av->m[v][3*i + 2] = (float)axes[i][2];
            av->m[v][9 + i] = (float)(-(axes[i][0]*C[0] + axes[i][1]*C[1] + axes[i][2]*C[2]));
        }
    }
}

extern "C" void kernel_launch(void* const* d_in, const int* in_sizes, int n_in,
                              void* d_out, int out_size, void* d_ws, size_t ws_size,
                              hipStream_t stream) {
    const float* pcd         = (const float*)d_in[0];
    const float* displace    = (const float*)d_in[1];
    const float* init_colors = (const float*)d_in[2];
    float* out = (float*)d_out;
    float* out_colors = out + (size_t)NVIEW * HW * 3;

    char* ws = (char*)d_ws;
    float4* srt = (float4*)(ws + WS_SRT);
    int* starts = (int*)(ws + WS_STARTS);

    AllViews av;
    compute_views(&av);

    prep_all<<<NVIEW, 1024, 0, stream>>>(pcd, displace, init_colors,
                                         out_colors, srt, starts, av);
    raster_kernel<<<NVIEW * (HW / 256), 256, 0, stream>>>(srt, starts, out);
}